// Round 3
// baseline (267.134 us; speedup 1.0000x reference)
//
#include <hip/hip_runtime.h>
#include <cmath>

#define PAD 68

// d_ws layout (floats):
//   [0      .. 1024)   ee[k] = numpy-pairwise sum of E[k][:]^2  (f32)
//   [1024   .. 2048)   counts[k]
//   [2048   .. 67584)  dw[k][d]  (1024*64)
//   [67584]            mse accumulator
//
// d_out layout (floats, concatenated in reference return order):
//   [0        .. 4194304)  quant_out (16,64,64,64)
//   [4194304]              loss
//   [4194305  .. 4259841)  idx (as float)
//   [4259841  .. 4325377)  new_embedding (1024,64)
//   [4325377  .. 4326401)  new_cs (1024)
//   [4326401  .. 4391937)  new_ema_w (1024,64)

__global__ __launch_bounds__(256) void vq_init_kernel(const float* __restrict__ E,
                                                      float* __restrict__ ws) {
    #pragma clang fp contract(off)
    int g = blockIdx.x * 256 + threadIdx.x;        // 256 blocks -> g in [0,65536)
    ws[2048 + g] = 0.0f;                           // zero dw
    if (g < 1024) {
        ws[1024 + g] = 0.0f;                       // zero counts
        const float* e = E + g * 64;
        // numpy pairwise_sum, n=64: 8 accumulators over strided chunks
        float r[8];
        #pragma unroll
        for (int j = 0; j < 8; ++j) r[j] = e[j] * e[j];
        #pragma unroll
        for (int t = 1; t < 8; ++t)
            #pragma unroll
            for (int j = 0; j < 8; ++j) {
                float sq = e[8 * t + j] * e[8 * t + j];
                r[j] = r[j] + sq;
            }
        ws[g] = ((r[0] + r[1]) + (r[2] + r[3])) + ((r[4] + r[5]) + (r[6] + r[7]));
    }
    if (g == 0) ws[67584] = 0.0f;                  // mse
}

__global__ __launch_bounds__(256) void vq_main_kernel(
    const float* __restrict__ x, const float* __restrict__ E,
    const float* __restrict__ R, float* __restrict__ ws, float* __restrict__ out)
{
    #pragma clang fp contract(off)
    __shared__ float s_x[64][PAD];    // [d][w]  raw x tile
    __shared__ float s_e[64][PAD];    // R [d][j] -> code chunk [c][d] -> quant [w][d]
    __shared__ float s_xr[64][PAD];   // [w][j]  rotated tokens (f32, == reference x_rot bits)
    __shared__ float s_ee[64];
    __shared__ float s_xx[64];
    __shared__ int   s_idx[64];
    __shared__ float s_red[8];

    const int tid = threadIdx.x;
    const int tc = tid >> 4;          // 0..15 token group   (w = tc + 16*i)
    const int tr = tid & 15;          // 0..15 code group    (c = tr + 16*j)
    const int brow = blockIdx.x;      // b*64 + h
    const int b = brow >> 6, h = brow & 63;

    const float* ee_g  = ws;
    float* counts  = ws + 1024;
    float* dw      = ws + 2048;
    float* mse_acc = ws + 67584;
    float* out_q   = out;
    float* out_idx = out + 4194305;

    const size_t xbase = (size_t)b * 262144 + (size_t)h * 64;

    // ---- stage x tile [d][w] and rotation matrix [d][j] ----
    #pragma unroll
    for (int i = 0; i < 4; ++i) {
        int d  = i * 16 + (tid >> 4);
        int w4 = (tid & 15) * 4;
        float4 v = *(const float4*)(x + xbase + (size_t)d * 4096 + w4);
        *(float4*)&s_x[d][w4] = v;
        float4 r = *(const float4*)(R + d * 64 + w4);
        *(float4*)&s_e[d][w4] = r;
    }
    __syncthreads();

    // ---- rotate: sequential-d f32 FMA chain (== BLAS sgemm order; R=+-1 exact) ----
    {
        float acc[4][4] = {};
        for (int d = 0; d < 64; ++d) {
            float xv[4], rv[4];
            #pragma unroll
            for (int i = 0; i < 4; ++i) xv[i] = s_x[d][tc + 16 * i];
            #pragma unroll
            for (int j = 0; j < 4; ++j) rv[j] = s_e[d][tr + 16 * j];
            #pragma unroll
            for (int i = 0; i < 4; ++i)
                #pragma unroll
                for (int j = 0; j < 4; ++j)
                    acc[i][j] = fmaf(xv[i], rv[j], acc[i][j]);
        }
        #pragma unroll
        for (int i = 0; i < 4; ++i)
            #pragma unroll
            for (int j = 0; j < 4; ++j)
                s_xr[tc + 16 * i][tr + 16 * j] = acc[i][j];
    }
    __syncthreads();

    // ---- xx[w] = numpy-pairwise sum of x_rot[w][:]^2 (bit-exact np.sum order) ----
    if (tid < 64) {
        const int w = tid;
        float r[8];
        #pragma unroll
        for (int j = 0; j < 8; ++j) { float u = s_xr[w][j]; r[j] = u * u; }
        #pragma unroll
        for (int t = 1; t < 8; ++t)
            #pragma unroll
            for (int j = 0; j < 8; ++j) {
                float u = s_xr[w][8 * t + j];
                float sq = u * u;
                r[j] = r[j] + sq;
            }
        s_xx[w] = ((r[0] + r[1]) + (r[2] + r[3])) + ((r[4] + r[5]) + (r[6] + r[7]));
    }
    __syncthreads();

    float xxw[4];
    #pragma unroll
    for (int i = 0; i < 4; ++i) xxw[i] = s_xx[tc + 16 * i];

    // ---- argmin of dist = fl(fl(xx+ee) - fl(2*m)), first-min tie-break ----
    float bestv[4]; int besti[4];
    #pragma unroll
    for (int i = 0; i < 4; ++i) { bestv[i] = 3.402823466e38f; besti[i] = 0; }

    for (int ch = 0; ch < 16; ++ch) {
        const int c0 = ch * 64;
        #pragma unroll
        for (int i = 0; i < 4; ++i) {                 // stage 64 codes [c][d]
            int f = i * 256 + tid;
            int c = f >> 4, d4 = (f & 15) * 4;
            float4 v = *(const float4*)(E + (size_t)(c0 + c) * 64 + d4);
            *(float4*)&s_e[c][d4] = v;
        }
        if (tid < 64) s_ee[tid] = ee_g[c0 + tid];
        __syncthreads();

        float acc[4][4] = {};
        #pragma unroll
        for (int dq = 0; dq < 16; ++dq) {             // sequential-d FMA chain per cell
            float4 xv[4], ev[4];
            #pragma unroll
            for (int i = 0; i < 4; ++i) xv[i] = *(const float4*)&s_xr[tc + 16 * i][dq * 4];
            #pragma unroll
            for (int j = 0; j < 4; ++j) ev[j] = *(const float4*)&s_e[tr + 16 * j][dq * 4];
            #pragma unroll
            for (int i = 0; i < 4; ++i)
                #pragma unroll
                for (int j = 0; j < 4; ++j) {
                    acc[i][j] = fmaf(xv[i].x, ev[j].x, acc[i][j]);
                    acc[i][j] = fmaf(xv[i].y, ev[j].y, acc[i][j]);
                    acc[i][j] = fmaf(xv[i].z, ev[j].z, acc[i][j]);
                    acc[i][j] = fmaf(xv[i].w, ev[j].w, acc[i][j]);
                }
        }
        #pragma unroll
        for (int j = 0; j < 4; ++j) {                 // c ascending within thread
            int c = c0 + tr + 16 * j;
            float eec = s_ee[tr + 16 * j];
            #pragma unroll
            for (int i = 0; i < 4; ++i) {
                float d1 = xxw[i] + eec;              // fl(xx+ee)
                float m2 = 2.0f * acc[i][j];          // exact
                float dist = d1 - m2;                 // fl(.. - ..)  (contract off)
                if (dist < bestv[i]) { bestv[i] = dist; besti[i] = c; }
            }
        }
        __syncthreads();
    }

    // ---- per-token min-reduce across the 16 code-group lanes; idx/counts/dw ----
    #pragma unroll
    for (int i = 0; i < 4; ++i) {
        float v = bestv[i]; int ix = besti[i];
        #pragma unroll
        for (int m = 1; m < 16; m <<= 1) {
            float ov = __shfl_xor(v, m, 64);
            int   oi = __shfl_xor(ix, m, 64);
            if (ov < v || (ov == v && oi < ix)) { v = ov; ix = oi; }
        }
        const int w = tc + 16 * i;
        if (tr == 0) {
            s_idx[w] = ix;
            out_idx[brow * 64 + w] = (float)ix;
            unsafeAtomicAdd(&counts[ix], 1.0f);
        }
        float4 xr = *(const float4*)&s_xr[w][tr * 4];
        float* dst = dw + (size_t)ix * 64 + tr * 4;
        unsafeAtomicAdd(dst + 0, xr.x);
        unsafeAtomicAdd(dst + 1, xr.y);
        unsafeAtomicAdd(dst + 2, xr.z);
        unsafeAtomicAdd(dst + 3, xr.w);
    }
    __syncthreads();

    // ---- gather quantized rows into s_e[w][d] ----
    {
        int w = tid >> 2, p = (tid & 3) * 16;
        int ix = s_idx[w];
        const float* erow = E + (size_t)ix * 64 + p;
        float4 a  = *(const float4*)(erow + 0);
        float4 b4 = *(const float4*)(erow + 4);
        float4 c4 = *(const float4*)(erow + 8);
        float4 d4 = *(const float4*)(erow + 12);
        *(float4*)&s_e[w][p + 0]  = a;
        *(float4*)&s_e[w][p + 4]  = b4;
        *(float4*)&s_e[w][p + 8]  = c4;
        *(float4*)&s_e[w][p + 12] = d4;
    }
    __syncthreads();

    // ---- straight-through output + mse ----
    float mse = 0.0f;
    #pragma unroll
    for (int i = 0; i < 4; ++i) {
        int d  = i * 16 + (tid >> 4);
        int w4 = (tid & 15) * 4;
        float4 xv = *(const float4*)&s_x[d][w4];
        float q0 = s_e[w4 + 0][d], q1 = s_e[w4 + 1][d];
        float q2 = s_e[w4 + 2][d], q3 = s_e[w4 + 3][d];
        float4 o;
        o.x = xv.x + (q0 - xv.x);
        o.y = xv.y + (q1 - xv.y);
        o.z = xv.z + (q2 - xv.z);
        o.w = xv.w + (q3 - xv.w);
        float dx = q0 - xv.x, dy = q1 - xv.y, dz = q2 - xv.z, dv = q3 - xv.w;
        mse = fmaf(dx, dx, mse); mse = fmaf(dy, dy, mse);
        mse = fmaf(dz, dz, mse); mse = fmaf(dv, dv, mse);
        *(float4*)(out_q + xbase + (size_t)d * 4096 + w4) = o;
    }
    #pragma unroll
    for (int off = 32; off > 0; off >>= 1) mse += __shfl_down(mse, off, 64);
    int wave = tid >> 6, lane = tid & 63;
    if (lane == 0) s_red[wave] = mse;
    __syncthreads();
    if (tid == 0)
        unsafeAtomicAdd(mse_acc, s_red[0] + s_red[1] + s_red[2] + s_red[3]);
}

__global__ __launch_bounds__(1024) void vq_finalize_kernel(
    const float* __restrict__ ema_cs, const float* __restrict__ ema_w,
    const float* __restrict__ ws, float* __restrict__ out)
{
    __shared__ float s_ncs[1024];
    __shared__ float s_red[32];
    const int t = threadIdx.x;
    const float* counts = ws + 1024;
    const float* dw     = ws + 2048;
    const float  mse    = ws[67584];

    float cnt = counts[t];
    float p   = cnt * (1.0f / 65536.0f);
    float ent = -p * logf(p + 1e-10f);
    float ncs = ema_cs[t] * 0.99f + 0.01f * cnt;

    float a = ncs, e2 = ent;
    #pragma unroll
    for (int off = 32; off > 0; off >>= 1) {
        a  += __shfl_down(a,  off, 64);
        e2 += __shfl_down(e2, off, 64);
    }
    const int wave = t >> 6;
    if ((t & 63) == 0) { s_red[wave] = a; s_red[16 + wave] = e2; }
    __syncthreads();
    if (t == 0) {
        float sa = 0.0f, se = 0.0f;
        for (int i = 0; i < 16; ++i) { sa += s_red[i]; se += s_red[16 + i]; }
        s_red[0] = sa; s_red[16] = se;
    }
    __syncthreads();
    const float n_tot = s_red[0], ent_tot = s_red[16];

    float ncs_s = (ncs + 1e-5f) / (n_tot + 1024.0f * 1e-5f) * n_tot;
    s_ncs[t] = ncs_s;

    float* out_loss = out + 4194304;
    float* out_emb  = out + 4259841;
    float* out_cs   = out + 4325377;
    float* out_emaw = out + 4326401;

    out_cs[t] = ncs_s;
    if (t == 0) out_loss[0] = 1.25f * (mse * (1.0f / 4194304.0f)) + ent_tot;
    __syncthreads();

    for (int i = 0; i < 64; ++i) {
        int e = i * 1024 + t;
        float nw = ema_w[e] * 0.99f + 0.01f * dw[e];
        out_emaw[e] = nw;
        out_emb[e]  = nw / s_ncs[e >> 6];
    }
}

extern "C" void kernel_launch(void* const* d_in, const int* in_sizes, int n_in,
                              void* d_out, int out_size, void* d_ws, size_t ws_size,
                              hipStream_t stream) {
    const float* x      = (const float*)d_in[0];
    const float* E      = (const float*)d_in[1];
    const float* R      = (const float*)d_in[2];
    const float* ema_cs = (const float*)d_in[3];
    const float* ema_w  = (const float*)d_in[4];
    float* out = (float*)d_out;
    float* ws  = (float*)d_ws;

    hipLaunchKernelGGL(vq_init_kernel,     dim3(256),  dim3(256),  0, stream, E, ws);
    hipLaunchKernelGGL(vq_main_kernel,     dim3(1024), dim3(256),  0, stream, x, E, R, ws, out);
    hipLaunchKernelGGL(vq_finalize_kernel, dim3(1),    dim3(1024), 0, stream, ema_cs, ema_w, ws, out);
}

// Round 4
// 251.864 us; speedup vs baseline: 1.0606x; 1.0606x over previous
//
#include <hip/hip_runtime.h>
#include <cmath>

#define PAD 68

// d_ws layout (floats):
//   [0      .. 1024)   ee[k] = numpy-pairwise sum of E[k][:]^2  (f32)
//   [1024   .. 2048)   counts[k]
//   [2048   .. 67584)  dw[k][d]  (1024*64)
//   [67584]            mse accumulator
//   [67585]            n_tot (written by reduce kernel)
//
// d_out layout (floats, concatenated in reference return order):
//   [0        .. 4194304)  quant_out (16,64,64,64)
//   [4194304]              loss
//   [4194305  .. 4259841)  idx (as float)
//   [4259841  .. 4325377)  new_embedding (1024,64)
//   [4325377  .. 4326401)  new_cs (1024)
//   [4326401  .. 4391937)  new_ema_w (1024,64)

__global__ __launch_bounds__(256) void vq_init_kernel(const float* __restrict__ E,
                                                      float* __restrict__ ws) {
    #pragma clang fp contract(off)
    int g = blockIdx.x * 256 + threadIdx.x;        // 256 blocks -> g in [0,65536)
    ws[2048 + g] = 0.0f;                           // zero dw
    if (g < 1024) {
        ws[1024 + g] = 0.0f;                       // zero counts
        const float* e = E + g * 64;
        // numpy pairwise_sum, n=64: 8 accumulators over strided chunks
        float r[8];
        #pragma unroll
        for (int j = 0; j < 8; ++j) r[j] = e[j] * e[j];
        #pragma unroll
        for (int t = 1; t < 8; ++t)
            #pragma unroll
            for (int j = 0; j < 8; ++j) {
                float sq = e[8 * t + j] * e[8 * t + j];
                r[j] = r[j] + sq;
            }
        ws[g] = ((r[0] + r[1]) + (r[2] + r[3])) + ((r[4] + r[5]) + (r[6] + r[7]));
    }
    if (g == 0) ws[67584] = 0.0f;                  // mse
}

__global__ __launch_bounds__(256, 4) void vq_main_kernel(
    const float* __restrict__ x, const float* __restrict__ E,
    const float* __restrict__ R, float* __restrict__ ws, float* __restrict__ out)
{
    #pragma clang fp contract(off)
    __shared__ float s_A[64][PAD];    // x [d][w] -> E chunk [c][d] -> quant [w][d]
    __shared__ float s_B[64][PAD];    // R [d][j] -> x_rot [w][j]
    __shared__ float s_ee[64];
    __shared__ float s_xx[64];
    __shared__ int   s_idx[64];
    __shared__ float s_red[8];

    const int tid = threadIdx.x;
    const int tc = tid >> 4;          // 0..15 token group   (w = tc + 16*i)
    const int tr = tid & 15;          // 0..15 code group    (c = tr + 16*j)
    const int brow = blockIdx.x;      // b*64 + h
    const int b = brow >> 6, h = brow & 63;

    const float* ee_g  = ws;
    float* counts  = ws + 1024;
    float* dw      = ws + 2048;
    float* mse_acc = ws + 67584;
    float* out_q   = out;
    float* out_idx = out + 4194305;

    const size_t xbase = (size_t)b * 262144 + (size_t)h * 64;

    // ---- stage x tile [d][w] into A and rotation matrix [d][j] into B ----
    #pragma unroll
    for (int i = 0; i < 4; ++i) {
        int d  = i * 16 + (tid >> 4);
        int w4 = (tid & 15) * 4;
        float4 v = *(const float4*)(x + xbase + (size_t)d * 4096 + w4);
        *(float4*)&s_A[d][w4] = v;
        float4 r = *(const float4*)(R + d * 64 + w4);
        *(float4*)&s_B[d][w4] = r;
    }
    __syncthreads();

    // ---- rotate: sequential-d f32 FMA chain (== BLAS sgemm order; R=+-1 exact) ----
    {
        float acc[4][4] = {};
        for (int d = 0; d < 64; ++d) {
            float xv[4], rv[4];
            #pragma unroll
            for (int i = 0; i < 4; ++i) xv[i] = s_A[d][tc + 16 * i];
            #pragma unroll
            for (int j = 0; j < 4; ++j) rv[j] = s_B[d][tr + 16 * j];
            #pragma unroll
            for (int i = 0; i < 4; ++i)
                #pragma unroll
                for (int j = 0; j < 4; ++j)
                    acc[i][j] = fmaf(xv[i], rv[j], acc[i][j]);
        }
        __syncthreads();              // all R reads done before overwrite
        #pragma unroll
        for (int i = 0; i < 4; ++i)
            #pragma unroll
            for (int j = 0; j < 4; ++j)
                s_B[tc + 16 * i][tr + 16 * j] = acc[i][j];
    }
    __syncthreads();

    // ---- xx[w] = numpy-pairwise sum of x_rot[w][:]^2 (bit-exact np.sum order) ----
    if (tid < 64) {
        const int w = tid;
        float r[8];
        #pragma unroll
        for (int j = 0; j < 8; ++j) { float u = s_B[w][j]; r[j] = u * u; }
        #pragma unroll
        for (int t = 1; t < 8; ++t)
            #pragma unroll
            for (int j = 0; j < 8; ++j) {
                float u = s_B[w][8 * t + j];
                float sq = u * u;
                r[j] = r[j] + sq;
            }
        s_xx[w] = ((r[0] + r[1]) + (r[2] + r[3])) + ((r[4] + r[5]) + (r[6] + r[7]));
    }
    __syncthreads();

    float xxw[4];
    #pragma unroll
    for (int i = 0; i < 4; ++i) xxw[i] = s_xx[tc + 16 * i];

    // ---- argmin of dist = fl(fl(xx+ee) - fl(2*m)), first-min tie-break ----
    float bestv[4]; int besti[4];
    #pragma unroll
    for (int i = 0; i < 4; ++i) { bestv[i] = 3.402823466e38f; besti[i] = 0; }

    for (int ch = 0; ch < 16; ++ch) {
        const int c0 = ch * 64;
        #pragma unroll
        for (int i = 0; i < 4; ++i) {                 // stage 64 codes [c][d] into A
            int f = i * 256 + tid;
            int c = f >> 4, d4 = (f & 15) * 4;
            float4 v = *(const float4*)(E + (size_t)(c0 + c) * 64 + d4);
            *(float4*)&s_A[c][d4] = v;
        }
        if (tid < 64) s_ee[tid] = ee_g[c0 + tid];
        __syncthreads();

        float acc[4][4] = {};
        #pragma unroll
        for (int dq = 0; dq < 16; ++dq) {
            float4 xv[4], ev[4];
            #pragma unroll
            for (int i = 0; i < 4; ++i) xv[i] = *(const float4*)&s_B[tc + 16 * i][dq * 4];
            #pragma unroll
            for (int j = 0; j < 4; ++j) ev[j] = *(const float4*)&s_A[tr + 16 * j][dq * 4];
            // k-substep interleave: 16 independent FMAs per step, per-cell chain
            // order (x -> y -> z -> w, dq ascending) is bit-identical to before.
            #pragma unroll
            for (int i = 0; i < 4; ++i)
                #pragma unroll
                for (int j = 0; j < 4; ++j)
                    acc[i][j] = fmaf(xv[i].x, ev[j].x, acc[i][j]);
            #pragma unroll
            for (int i = 0; i < 4; ++i)
                #pragma unroll
                for (int j = 0; j < 4; ++j)
                    acc[i][j] = fmaf(xv[i].y, ev[j].y, acc[i][j]);
            #pragma unroll
            for (int i = 0; i < 4; ++i)
                #pragma unroll
                for (int j = 0; j < 4; ++j)
                    acc[i][j] = fmaf(xv[i].z, ev[j].z, acc[i][j]);
            #pragma unroll
            for (int i = 0; i < 4; ++i)
                #pragma unroll
                for (int j = 0; j < 4; ++j)
                    acc[i][j] = fmaf(xv[i].w, ev[j].w, acc[i][j]);
        }
        #pragma unroll
        for (int j = 0; j < 4; ++j) {                 // c ascending within thread
            int c = c0 + tr + 16 * j;
            float eec = s_ee[tr + 16 * j];
            #pragma unroll
            for (int i = 0; i < 4; ++i) {
                float d1 = xxw[i] + eec;              // fl(xx+ee)
                float m2 = 2.0f * acc[i][j];          // exact
                float dist = d1 - m2;                 // fl(.. - ..)  (contract off)
                if (dist < bestv[i]) { bestv[i] = dist; besti[i] = c; }
            }
        }
        __syncthreads();
    }

    // ---- per-token min-reduce across the 16 code-group lanes; idx/counts/dw ----
    #pragma unroll
    for (int i = 0; i < 4; ++i) {
        float v = bestv[i]; int ix = besti[i];
        #pragma unroll
        for (int m = 1; m < 16; m <<= 1) {
            float ov = __shfl_xor(v, m, 64);
            int   oi = __shfl_xor(ix, m, 64);
            if (ov < v || (ov == v && oi < ix)) { v = ov; ix = oi; }
        }
        const int w = tc + 16 * i;
        if (tr == 0) {
            s_idx[w] = ix;
            out_idx[brow * 64 + w] = (float)ix;
            unsafeAtomicAdd(&counts[ix], 1.0f);
        }
        float4 xr = *(const float4*)&s_B[w][tr * 4];
        float* dst = dw + (size_t)ix * 64 + tr * 4;
        unsafeAtomicAdd(dst + 0, xr.x);
        unsafeAtomicAdd(dst + 1, xr.y);
        unsafeAtomicAdd(dst + 2, xr.z);
        unsafeAtomicAdd(dst + 3, xr.w);
    }
    __syncthreads();

    // ---- gather quantized rows into A[w][d] ----
    {
        int w = tid >> 2, p = (tid & 3) * 16;
        int ix = s_idx[w];
        const float* erow = E + (size_t)ix * 64 + p;
        float4 a  = *(const float4*)(erow + 0);
        float4 b4 = *(const float4*)(erow + 4);
        float4 c4 = *(const float4*)(erow + 8);
        float4 d4 = *(const float4*)(erow + 12);
        *(float4*)&s_A[w][p + 0]  = a;
        *(float4*)&s_A[w][p + 4]  = b4;
        *(float4*)&s_A[w][p + 8]  = c4;
        *(float4*)&s_A[w][p + 12] = d4;
    }
    __syncthreads();

    // ---- straight-through output + mse (x re-read from global; L2-resident) ----
    float mse = 0.0f;
    #pragma unroll
    for (int i = 0; i < 4; ++i) {
        int d  = i * 16 + (tid >> 4);
        int w4 = (tid & 15) * 4;
        float4 xv = *(const float4*)(x + xbase + (size_t)d * 4096 + w4);
        float q0 = s_A[w4 + 0][d], q1 = s_A[w4 + 1][d];
        float q2 = s_A[w4 + 2][d], q3 = s_A[w4 + 3][d];
        float4 o;
        o.x = xv.x + (q0 - xv.x);
        o.y = xv.y + (q1 - xv.y);
        o.z = xv.z + (q2 - xv.z);
        o.w = xv.w + (q3 - xv.w);
        float dx = q0 - xv.x, dy = q1 - xv.y, dz = q2 - xv.z, dv = q3 - xv.w;
        mse = fmaf(dx, dx, mse); mse = fmaf(dy, dy, mse);
        mse = fmaf(dz, dz, mse); mse = fmaf(dv, dv, mse);
        *(float4*)(out_q + xbase + (size_t)d * 4096 + w4) = o;
    }
    #pragma unroll
    for (int off = 32; off > 0; off >>= 1) mse += __shfl_down(mse, off, 64);
    int wave = tid >> 6, lane = tid & 63;
    if (lane == 0) s_red[wave] = mse;
    __syncthreads();
    if (tid == 0)
        unsafeAtomicAdd(mse_acc, s_red[0] + s_red[1] + s_red[2] + s_red[3]);
}

// 1 block: entropy + n_tot + loss + new_cs
__global__ __launch_bounds__(1024) void vq_reduce_kernel(
    const float* __restrict__ ema_cs, float* __restrict__ ws, float* __restrict__ out)
{
    __shared__ float s_red[32];
    const int t = threadIdx.x;
    const float* counts = ws + 1024;
    const float  mse    = ws[67584];

    float cnt = counts[t];
    float p   = cnt * (1.0f / 65536.0f);
    float ent = -p * logf(p + 1e-10f);
    float ncs = ema_cs[t] * 0.99f + 0.01f * cnt;

    float a = ncs, e2 = ent;
    #pragma unroll
    for (int off = 32; off > 0; off >>= 1) {
        a  += __shfl_down(a,  off, 64);
        e2 += __shfl_down(e2, off, 64);
    }
    const int wave = t >> 6;
    if ((t & 63) == 0) { s_red[wave] = a; s_red[16 + wave] = e2; }
    __syncthreads();
    if (t == 0) {
        float sa = 0.0f, se = 0.0f;
        for (int i = 0; i < 16; ++i) { sa += s_red[i]; se += s_red[16 + i]; }
        s_red[0] = sa; s_red[16] = se;
    }
    __syncthreads();
    const float n_tot = s_red[0], ent_tot = s_red[16];

    float ncs_s = (ncs + 1e-5f) / (n_tot + 1024.0f * 1e-5f) * n_tot;
    out[4325377 + t] = ncs_s;                       // new_cs
    if (t == 0) {
        out[4194304] = 1.25f * (mse * (1.0f / 4194304.0f)) + ent_tot;  // loss
        ws[67585] = n_tot;
    }
}

// 16 blocks x 256: new_ema_w + new_embedding (64 codes x 64 dims per block)
__global__ __launch_bounds__(256) void vq_update_kernel(
    const float* __restrict__ ema_cs, const float* __restrict__ ema_w,
    const float* __restrict__ ws, float* __restrict__ out)
{
    __shared__ float s_inv[64];
    const int t = threadIdx.x;
    const int base_code = blockIdx.x * 64;
    const float* counts = ws + 1024;
    const float* dw     = ws + 2048;
    const float  n_tot  = ws[67585];

    if (t < 64) {
        int code = base_code + t;
        float ncs = ema_cs[code] * 0.99f + 0.01f * counts[code];
        float ncs_s = (ncs + 1e-5f) / (n_tot + 1024.0f * 1e-5f) * n_tot;
        s_inv[t] = 1.0f / ncs_s;
    }
    __syncthreads();

    float* out_emb  = out + 4259841;
    float* out_emaw = out + 4326401;
    const int base_e = base_code * 64;

    #pragma unroll
    for (int k = 0; k < 16; ++k) {
        int el = k * 256 + t;                 // 0..4095 within block
        int e  = base_e + el;
        float nw = ema_w[e] * 0.99f + 0.01f * dw[e];
        out_emaw[e] = nw;
        out_emb[e]  = nw * s_inv[el >> 6];
    }
}

extern "C" void kernel_launch(void* const* d_in, const int* in_sizes, int n_in,
                              void* d_out, int out_size, void* d_ws, size_t ws_size,
                              hipStream_t stream) {
    const float* x      = (const float*)d_in[0];
    const float* E      = (const float*)d_in[1];
    const float* R      = (const float*)d_in[2];
    const float* ema_cs = (const float*)d_in[3];
    const float* ema_w  = (const float*)d_in[4];
    float* out = (float*)d_out;
    float* ws  = (float*)d_ws;

    hipLaunchKernelGGL(vq_init_kernel,   dim3(256),  dim3(256),  0, stream, E, ws);
    hipLaunchKernelGGL(vq_main_kernel,   dim3(1024), dim3(256),  0, stream, x, E, R, ws, out);
    hipLaunchKernelGGL(vq_reduce_kernel, dim3(1),    dim3(1024), 0, stream, ema_cs, ws, out);
    hipLaunchKernelGGL(vq_update_kernel, dim3(16),   dim3(256),  0, stream, ema_cs, ema_w, ws, out);
}